// Round 6
// baseline (263.892 us; speedup 1.0000x reference)
//
#include <hip/hip_runtime.h>
#include <hip/hip_bf16.h>

typedef __bf16 bf16_t;
typedef __bf16 bf16x8 __attribute__((ext_vector_type(8)));
typedef float f32x4 __attribute__((ext_vector_type(4)));
typedef unsigned short u16x4 __attribute__((ext_vector_type(4)));

// NOTE operand order: A = weight fragment (gate rows), B = x/h fragment
// (batch cols). A- and B-fragment lane mappings are identical on gfx950
// (lane&15 = non-K index, (lane>>4)*8+j = K), so the staged layouts serve
// either operand. C/D: col(lane&15) = batch, row(quad*4+r) = gate row.
#define MFMA16(a, b, c) __builtin_amdgcn_mfma_f32_16x16x32_bf16((a), (b), (c), 0, 0, 0)

// Problem constants
#define BATCH 4096
#define SEQN 128
#define HN 256
#define NLABELS 100
#define TSTEPS 32
#define LEN_VN 1500
#define IPD_VN 256

// Workspace layout (bytes, 256-aligned)
#define OFF_LENT   0u           // 1500*64*4 = 384000
#define OFF_IPDT   384000u      // 256*64*4  = 65536
#define OFF_WIH    449536u      // 768*256*2 = 393216
#define OFF_WHH    842752u      // 393216
#define OFF_GI     1235968u     // 4096*32*768*2 = 201326592
#define WS_NEEDED  202562560u

__device__ __forceinline__ float sigf(float x) {
    return __builtin_amdgcn_rcpf(1.f + __expf(-x));
}
__device__ __forceinline__ float tanh_fast(float x) {
    return 2.f * __builtin_amdgcn_rcpf(1.f + __expf(-2.f * x)) - 1.f;
}
__device__ __forceinline__ float b2f(unsigned short v) {
    union { unsigned u; float f; } c; c.u = ((unsigned)v) << 16; return c.f;
}
__device__ __forceinline__ unsigned short f2b(float f) {
    union { bf16_t h; unsigned short s; } c; c.h = (bf16_t)f; return c.s;
}

// LDS-only barrier: does not drain vmcnt, global loads/stores stay in flight.
__device__ __forceinline__ void barrier_lds() {
    asm volatile("s_waitcnt lgkmcnt(0)\n\ts_barrier" ::: "memory");
}

// ---------------------------------------------------------------------------
// K1: prep. blocks [0,439): fused embed+FC tables. [439,631): weight frags.
// ---------------------------------------------------------------------------
__global__ void prep_kernel(const float* __restrict__ len_emb,
                            const float* __restrict__ ipd_emb,
                            const float* __restrict__ fc_w,
                            const float* __restrict__ fc_b,
                            const float* __restrict__ w_ih,
                            const float* __restrict__ w_hh,
                            float* __restrict__ lenT, float* __restrict__ ipdT,
                            bf16_t* __restrict__ wfrag_ih,
                            bf16_t* __restrict__ wfrag_hh) {
    const int bid = blockIdx.x, tid = threadIdx.x;
    if (bid < 439) {
        const int row = bid * 4 + (tid >> 6);
        const int e = tid & 63;
        if (row < LEN_VN) {
            const float* emb = len_emb + row * 64;
            const float* wv = fc_w + e * 128;
            float s = fc_b[e];
            #pragma unroll 8
            for (int j = 0; j < 64; ++j) s += emb[j] * wv[j];
            lenT[row * 64 + e] = s;
        } else if (row < LEN_VN + IPD_VN) {
            const int v = row - LEN_VN;
            const float* emb = ipd_emb + v * 64;
            const float* wv = fc_w + e * 128 + 64;
            float s = 0.f;
            #pragma unroll 8
            for (int j = 0; j < 64; ++j) s += emb[j] * wv[j];
            ipdT[v * 64 + e] = s;
        }
    } else {
        // frag order: wfrag[ct(48)][kt(8)][lane(64)][8], value =
        // W[ct*16 + (lane&15)][kt*32 + (lane>>4)*8 + j]
        const int flat = (bid - 439) * 256 + tid;   // 0..49151
        const int which = flat / 24576;
        const int rem = flat % 24576;
        const int c = rem >> 9;
        const int kt = (rem >> 6) & 7;
        const int lane = rem & 63;
        const int g = c * 16 + (lane & 15);
        const int k0 = kt * 32 + (lane >> 4) * 8;
        const float* src = (which == 0 ? w_ih : w_hh) + g * 256 + k0;
        bf16_t* dst = (which == 0 ? wfrag_ih : wfrag_hh) + ((c * 8 + kt) * 64 + lane) * 8;
        f32x4 s0 = *(const f32x4*)(src);
        f32x4 s1 = *(const f32x4*)(src + 4);
        bf16x8 o;
        #pragma unroll
        for (int j = 0; j < 4; ++j) { o[j] = (bf16_t)s0[j]; o[4 + j] = (bf16_t)s1[j]; }
        *(bf16x8*)dst = o;
    }
}

// ---------------------------------------------------------------------------
// K2: input-side GEMM + fused gather + bias fold. 256 blocks x 512 threads
// (8 waves, 2 waves/SIMD, 256-VGPR budget). Block owns 16 batch rows.
// Wave w owns gate tiles {2w,2w+1,16+2w,17+2w,32+2w} in REGISTERS (160 VGPR)
// and {33+2w} in LDS (64 KB). A-tile double-buffered, one lgkm-barrier/step.
// gi layout: [bt][ct(48)][t(32)][lane(64)][r(4)], value =
//   gate[ct*16+(lane>>4)*4+r][batch bt*16+(lane&15)], biases pre-added
//   (r,z: b_ih+b_hh; n: b_ih only).
// ---------------------------------------------------------------------------
__global__ void __launch_bounds__(512, 2)
gemm_gi(const int* __restrict__ len_x, const int* __restrict__ ipd_x,
        const float* __restrict__ lenT, const float* __restrict__ ipdT,
        const bf16_t* __restrict__ wfrag_ih,
        const float* __restrict__ b_ih, const float* __restrict__ b_hh,
        bf16_t* __restrict__ gi) {
    __shared__ bf16_t wlds[8 * 8 * 512];    // 64 KB: per-wave 6th tile
    __shared__ bf16_t a_lds[2][8 * 512];    // 2 x 8 KB A-tile double buffer

    const int tid = threadIdx.x;
    const int lane = tid & 63;
    const int w = tid >> 6;          // wave 0..7
    const int bt = blockIdx.x;
    const int quad = lane >> 4;

    const int cts[6] = {2*w, 2*w + 1, 16 + 2*w, 17 + 2*w, 32 + 2*w, 33 + 2*w};

    // 5 register weight tiles, 6th to LDS
    bf16x8 wr[5][8];
    #pragma unroll
    for (int cc = 0; cc < 5; ++cc)
        #pragma unroll
        for (int kt = 0; kt < 8; ++kt)
            wr[cc][kt] = *(const bf16x8*)(wfrag_ih + ((cts[cc] * 8 + kt) * 64 + lane) * 8);
    #pragma unroll
    for (int kt = 0; kt < 8; ++kt)
        *(bf16x8*)&wlds[(w * 8 + kt) * 512 + lane * 8] =
            *(const bf16x8*)(wfrag_ih + ((cts[5] * 8 + kt) * 64 + lane) * 8);

    // biases per lane: gate rows cts[cc]*16 + quad*4 + {0..3}
    f32x4 bias[6];
    #pragma unroll
    for (int cc = 0; cc < 6; ++cc) {
        f32x4 v = *(const f32x4*)(b_ih + cts[cc] * 16 + quad * 4);
        if (cc < 4) v += *(const f32x4*)(b_hh + cts[cc] * 16 + quad * 4);
        bias[cc] = v;
    }

    // gather: 512 threads cover one t-slice (16 rows x 256 k)
    const int b_row = bt * 16 + (lane & 15);
    const int k0 = w * 32 + quad * 8;
    const int p = k0 >> 6;
    const int e0 = k0 & 63;

    auto do_gather = [&](int t) {
        const int seq = t * 4 + p;
        const int v1 = len_x[b_row * SEQN + seq];
        const int v2 = ipd_x[b_row * SEQN + seq];
        const f32x4* lp = (const f32x4*)(lenT + v1 * 64 + e0);
        const f32x4* ip = (const f32x4*)(ipdT + v2 * 64 + e0);
        f32x4 a0 = lp[0] + ip[0];
        f32x4 a1 = lp[1] + ip[1];
        bf16x8 o;
        #pragma unroll
        for (int j = 0; j < 4; ++j) { o[j] = (bf16_t)a0[j]; o[4 + j] = (bf16_t)a1[j]; }
        *(bf16x8*)&a_lds[t & 1][w * 512 + lane * 8] = o;
    };

    do_gather(0);
    bf16_t* gib = gi + (size_t)bt * 48 * 32 * 256 + lane * 4;
    const bf16_t* wb = &wlds[w * 8 * 512 + lane * 8];

    for (int t = 0; t < TSTEPS; ++t) {
        barrier_lds();
        if (t + 1 < TSTEPS) do_gather(t + 1);

        f32x4 acc[6] = {};
        const bf16_t* ab = &a_lds[t & 1][lane * 8];
        #pragma unroll
        for (int kt = 0; kt < 8; ++kt) {
            bf16x8 xf = *(const bf16x8*)(ab + kt * 512);
            bf16x8 w5 = *(const bf16x8*)(wb + kt * 512);
            acc[0] = MFMA16(wr[0][kt], xf, acc[0]);
            acc[1] = MFMA16(wr[1][kt], xf, acc[1]);
            acc[2] = MFMA16(wr[2][kt], xf, acc[2]);
            acc[3] = MFMA16(wr[3][kt], xf, acc[3]);
            acc[4] = MFMA16(wr[4][kt], xf, acc[4]);
            acc[5] = MFMA16(w5, xf, acc[5]);
        }

        #pragma unroll
        for (int cc = 0; cc < 6; ++cc) {
            u16x4 o;
            #pragma unroll
            for (int r = 0; r < 4; ++r) o[r] = f2b(acc[cc][r] + bias[cc][r]);
            *(u16x4*)(gib + ((size_t)cts[cc] * 32 + t) * 256) = o;   // stays in flight
        }
    }
}

// ---------------------------------------------------------------------------
// K3: recurrent GRU. 256 blocks x 512 threads (8 waves); block owns 16 batch
// rows. Wave w: 5 register tiles + 1 LDS tile (as K2). h double-buffered in
// LDS; epilogue lane holds 4 CONSECUTIVE hidden cols -> ds_write_b64.
// One lgkm-barrier per step. h_fin aliases wlds post-loop.
// ---------------------------------------------------------------------------
__global__ void __launch_bounds__(512, 2)
gru_kernel(const bf16_t* __restrict__ gi,
           const bf16_t* __restrict__ wfrag_hh,
           const float* __restrict__ b_hh,
           const float* __restrict__ out_w,
           const float* __restrict__ out_b,
           float* __restrict__ out) {
    __shared__ char smem[81920];
    bf16_t* wlds = (bf16_t*)smem;                 // 64 KB: per-wave 6th tile
    bf16_t* h_lds = (bf16_t*)(smem + 65536);      // 2 x 8 KB double buffer
    float* h_fin = (float*)smem;                  // aliases wlds (post-loop)

    const int tid = threadIdx.x;
    const int lane = tid & 63;
    const int w = tid >> 6;
    const int bt = blockIdx.x;
    const int quad = lane >> 4;
    const int b = lane & 15;

    const int cts[6] = {2*w, 2*w + 1, 16 + 2*w, 17 + 2*w, 32 + 2*w, 33 + 2*w};

    bf16x8 wr[5][8];
    #pragma unroll
    for (int cc = 0; cc < 5; ++cc)
        #pragma unroll
        for (int kt = 0; kt < 8; ++kt)
            wr[cc][kt] = *(const bf16x8*)(wfrag_hh + ((cts[cc] * 8 + kt) * 64 + lane) * 8);
    #pragma unroll
    for (int kt = 0; kt < 8; ++kt)
        *(bf16x8*)&wlds[(w * 8 + kt) * 512 + lane * 8] =
            *(const bf16x8*)(wfrag_hh + ((cts[5] * 8 + kt) * 64 + lane) * 8);

    // n-gate hidden biases: rows cts[4+s]*16 + quad*4 + {0..3}
    f32x4 bhn[2];
    bhn[0] = *(const f32x4*)(b_hh + cts[4] * 16 + quad * 4);
    bhn[1] = *(const f32x4*)(b_hh + cts[5] * 16 + quad * 4);

    // zero the t=0 read buffer (buf index 1)
    for (int i = tid; i < 4096; i += 512) h_lds[4096 + i] = (bf16_t)0.f;

    // write offsets: subtile s covers hidden cols j0 = 32w + 16s + 4*quad,
    // 4 consecutive cols -> u16x4 (8 B) into the frag layout:
    // off = w*512 + (((2s + (quad>>1)) & 3)*16 + b)*8 + 4*(quad&1)
    int woff[2];
    #pragma unroll
    for (int s = 0; s < 2; ++s)
        woff[s] = w * 512 + (((2 * s + (quad >> 1)) & 3) * 16 + b) * 8 + 4 * (quad & 1);

    f32x4 hprev[2] = {};
    const bf16_t* gib = gi + (size_t)bt * 48 * 32 * 256 + lane * 4;
    const bf16_t* wb = &wlds[w * 8 * 512 + lane * 8];

    for (int t = 0; t < TSTEPS; ++t) {
        barrier_lds();                            // prev step's h writes visible

        u16x4 g[6];
        #pragma unroll
        for (int cc = 0; cc < 6; ++cc)
            g[cc] = *(const u16x4*)(gib + ((size_t)cts[cc] * 32 + t) * 256);

        const bf16_t* hb = &h_lds[((t + 1) & 1) * 4096 + lane * 8];
        f32x4 acc[6] = {};
        #pragma unroll
        for (int kt = 0; kt < 8; ++kt) {
            bf16x8 hf = *(const bf16x8*)(hb + kt * 512);
            bf16x8 w5 = *(const bf16x8*)(wb + kt * 512);
            acc[0] = MFMA16(wr[0][kt], hf, acc[0]);
            acc[1] = MFMA16(wr[1][kt], hf, acc[1]);
            acc[2] = MFMA16(wr[2][kt], hf, acc[2]);
            acc[3] = MFMA16(wr[3][kt], hf, acc[3]);
            acc[4] = MFMA16(wr[4][kt], hf, acc[4]);
            acc[5] = MFMA16(w5, hf, acc[5]);
        }

        bf16_t* hwb = &h_lds[(t & 1) * 4096];
        #pragma unroll
        for (int s = 0; s < 2; ++s) {
            u16x4 o;
            #pragma unroll
            for (int r = 0; r < 4; ++r) {
                float rg = sigf(acc[s][r] + b2f(g[s][r]));
                float zg = sigf(acc[2 + s][r] + b2f(g[2 + s][r]));
                float ng = tanh_fast(b2f(g[4 + s][r]) + rg * (acc[4 + s][r] + bhn[s][r]));
                float hn = ng + zg * (hprev[s][r] - ng);
                hprev[s][r] = hn;
                o[r] = f2b(hn);
            }
            *(u16x4*)(hwb + woff[s]) = o;         // one ds_write_b64
        }
    }

    __syncthreads();       // all waves done reading wlds -> safe to alias h_fin

    #pragma unroll
    for (int s = 0; s < 2; ++s)
        *(f32x4*)(h_fin + b * 260 + 32 * w + 16 * s + 4 * quad) = hprev[s];
    __syncthreads();

    for (int i = tid; i < 16 * NLABELS; i += 512) {
        const int row = i / NLABELS;
        const int cl = i - row * NLABELS;
        const f32x4* wrow = (const f32x4*)(out_w + cl * 256);
        const f32x4* hr = (const f32x4*)(h_fin + row * 260);
        f32x4 acc = {0.f, 0.f, 0.f, 0.f};
        #pragma unroll 4
        for (int k = 0; k < 64; ++k) acc += hr[k] * wrow[k];
        out[(bt * 16 + row) * NLABELS + cl] =
            out_b[cl] + acc[0] + acc[1] + acc[2] + acc[3];
    }
}

// ---------------------------------------------------------------------------
extern "C" void kernel_launch(void* const* d_in, const int* in_sizes, int n_in,
                              void* d_out, int out_size, void* d_ws, size_t ws_size,
                              hipStream_t stream) {
    (void)in_sizes; (void)n_in; (void)out_size; (void)ws_size;
    const int*   len_x   = (const int*)d_in[0];
    const int*   ipd_x   = (const int*)d_in[1];
    const float* len_emb = (const float*)d_in[2];
    const float* ipd_emb = (const float*)d_in[3];
    const float* fc_w    = (const float*)d_in[4];
    const float* fc_b    = (const float*)d_in[5];
    const float* w_ih    = (const float*)d_in[6];
    const float* w_hh    = (const float*)d_in[7];
    const float* b_ih    = (const float*)d_in[8];
    const float* b_hh    = (const float*)d_in[9];
    const float* out_w   = (const float*)d_in[10];
    const float* out_b   = (const float*)d_in[11];

    char* ws = (char*)d_ws;
    float*  lenT = (float*)(ws + OFF_LENT);
    float*  ipdT = (float*)(ws + OFF_IPDT);
    bf16_t* wfi  = (bf16_t*)(ws + OFF_WIH);
    bf16_t* wfh  = (bf16_t*)(ws + OFF_WHH);
    bf16_t* gi   = (bf16_t*)(ws + OFF_GI);

    prep_kernel<<<631, 256, 0, stream>>>(len_emb, ipd_emb, fc_w, fc_b,
                                         w_ih, w_hh, lenT, ipdT, wfi, wfh);
    gemm_gi<<<256, 512, 0, stream>>>(len_x, ipd_x, lenT, ipdT, wfi,
                                     b_ih, b_hh, gi);
    gru_kernel<<<256, 512, 0, stream>>>(gi, wfh, b_hh, out_w, out_b,
                                        (float*)d_out);
}

// Round 7
// 234.351 us; speedup vs baseline: 1.1261x; 1.1261x over previous
//
#include <hip/hip_runtime.h>
#include <hip/hip_bf16.h>

typedef __bf16 bf16_t;
typedef __bf16 bf16x8 __attribute__((ext_vector_type(8)));
typedef float f32x4 __attribute__((ext_vector_type(4)));
typedef unsigned short u16x4 __attribute__((ext_vector_type(4)));

// Operand order: A = weight fragment (gate rows), B = x/h fragment (batch).
// C/D: col(lane&15) = batch, row(quad*4+r) = gate row.
#define MFMA16(a, b, c) __builtin_amdgcn_mfma_f32_16x16x32_bf16((a), (b), (c), 0, 0, 0)

#define BATCH 4096
#define SEQN 128
#define HN 256
#define NLABELS 100
#define TSTEPS 32
#define LEN_VN 1500
#define IPD_VN 256

// Workspace layout (bytes)
#define OFF_LENT   0u           // 1500*64*4 = 384000
#define OFF_IPDT   384000u      // 256*64*4  = 65536
#define OFF_WIH    449536u      // 768*256*2 = 393216
#define OFF_WHH    842752u      // 393216
#define OFF_GI     1235968u     // 4096*32*768*2 = 201326592

__device__ __forceinline__ float sigf(float x) {
    return __builtin_amdgcn_rcpf(1.f + __expf(-x));
}
__device__ __forceinline__ float tanh_fast(float x) {
    return 2.f * __builtin_amdgcn_rcpf(1.f + __expf(-2.f * x)) - 1.f;
}
__device__ __forceinline__ float b2f(unsigned short v) {
    union { unsigned u; float f; } c; c.u = ((unsigned)v) << 16; return c.f;
}
__device__ __forceinline__ f32x4 b2f4(u16x4 v) {
    f32x4 o;
    #pragma unroll
    for (int r = 0; r < 4; ++r) o[r] = b2f(v[r]);
    return o;
}
__device__ __forceinline__ unsigned short f2b(float f) {
    union { bf16_t h; unsigned short s; } c; c.h = (bf16_t)f; return c.s;
}

// LDS-only barrier: does not drain vmcnt; global loads/stores stay in flight.
__device__ __forceinline__ void barrier_lds() {
    asm volatile("s_waitcnt lgkmcnt(0)\n\ts_barrier" ::: "memory");
}

// ---------------------------------------------------------------------------
// K1: prep. blocks [0,439): fused embed+FC tables. [439,631): weight frags.
// frag order: wfrag[ct(48)][kt(8)][lane(64)][8], value =
//   W[ct*16 + (lane&15)][kt*32 + (lane>>4)*8 + j]
// ---------------------------------------------------------------------------
__global__ void prep_kernel(const float* __restrict__ len_emb,
                            const float* __restrict__ ipd_emb,
                            const float* __restrict__ fc_w,
                            const float* __restrict__ fc_b,
                            const float* __restrict__ w_ih,
                            const float* __restrict__ w_hh,
                            float* __restrict__ lenT, float* __restrict__ ipdT,
                            bf16_t* __restrict__ wfrag_ih,
                            bf16_t* __restrict__ wfrag_hh) {
    const int bid = blockIdx.x, tid = threadIdx.x;
    if (bid < 439) {
        const int row = bid * 4 + (tid >> 6);
        const int e = tid & 63;
        if (row < LEN_VN) {
            const float* emb = len_emb + row * 64;
            const float* wv = fc_w + e * 128;
            float s = fc_b[e];
            #pragma unroll 8
            for (int j = 0; j < 64; ++j) s += emb[j] * wv[j];
            lenT[row * 64 + e] = s;
        } else if (row < LEN_VN + IPD_VN) {
            const int v = row - LEN_VN;
            const float* emb = ipd_emb + v * 64;
            const float* wv = fc_w + e * 128 + 64;
            float s = 0.f;
            #pragma unroll 8
            for (int j = 0; j < 64; ++j) s += emb[j] * wv[j];
            ipdT[v * 64 + e] = s;
        }
    } else {
        const int flat = (bid - 439) * 256 + tid;   // 0..49151
        const int which = flat / 24576;
        const int rem = flat % 24576;
        const int c = rem >> 9;
        const int kt = (rem >> 6) & 7;
        const int lane = rem & 63;
        const int g = c * 16 + (lane & 15);
        const int k0 = kt * 32 + (lane >> 4) * 8;
        const float* src = (which == 0 ? w_ih : w_hh) + g * 256 + k0;
        bf16_t* dst = (which == 0 ? wfrag_ih : wfrag_hh) + ((c * 8 + kt) * 64 + lane) * 8;
        f32x4 s0 = *(const f32x4*)(src);
        f32x4 s1 = *(const f32x4*)(src + 4);
        bf16x8 o;
        #pragma unroll
        for (int j = 0; j < 4; ++j) { o[j] = (bf16_t)s0[j]; o[4 + j] = (bf16_t)s1[j]; }
        *(bf16x8*)dst = o;
    }
}

// ---------------------------------------------------------------------------
// K2: input-side GEMM + fused OCTET-COALESCED gather + bias-init.
// 256 blocks x 512 threads (8 waves, 2/SIMD). Block owns 16 batch rows.
// Wave w: gate tiles {2w,2w+1,16+2w,17+2w,32+2w} in regs, {33+2w} in LDS.
// Gather: 8 threads per (row,seq) pair, each loads 32 B consecutive from
// each table row -> ~8 cache lines per vector load instr (TA-coalesced).
// gi layout: [bt][ct(48)][t(32)][lane(64)][r(4)], biases pre-added
// (r,z: b_ih+b_hh; n: b_ih only).
// ---------------------------------------------------------------------------
__global__ void __launch_bounds__(512, 2)
gemm_gi(const int* __restrict__ len_x, const int* __restrict__ ipd_x,
        const float* __restrict__ lenT, const float* __restrict__ ipdT,
        const bf16_t* __restrict__ wfrag_ih,
        const float* __restrict__ b_ih, const float* __restrict__ b_hh,
        bf16_t* __restrict__ gi) {
    __shared__ bf16_t wlds[8 * 8 * 512];    // 64 KB: per-wave 6th tile
    __shared__ bf16_t a_lds[2][8 * 512];    // 2 x 8 KB A-tile double buffer

    const int tid = threadIdx.x;
    const int lane = tid & 63;
    const int w = tid >> 6;
    const int bt = blockIdx.x;
    const int quad = lane >> 4;

    const int cts[6] = {2*w, 2*w + 1, 16 + 2*w, 17 + 2*w, 32 + 2*w, 33 + 2*w};

    bf16x8 wr[5][8];
    #pragma unroll
    for (int cc = 0; cc < 5; ++cc)
        #pragma unroll
        for (int kt = 0; kt < 8; ++kt)
            wr[cc][kt] = *(const bf16x8*)(wfrag_ih + ((cts[cc] * 8 + kt) * 64 + lane) * 8);
    #pragma unroll
    for (int kt = 0; kt < 8; ++kt)
        *(bf16x8*)&wlds[(w * 8 + kt) * 512 + lane * 8] =
            *(const bf16x8*)(wfrag_ih + ((cts[5] * 8 + kt) * 64 + lane) * 8);

    // biases = acc init values: gate rows cts[cc]*16 + quad*4 + {0..3}
    f32x4 bias[6];
    #pragma unroll
    for (int cc = 0; cc < 6; ++cc) {
        f32x4 v = *(const f32x4*)(b_ih + cts[cc] * 16 + quad * 4);
        if (cc < 4) v += *(const f32x4*)(b_hh + cts[cc] * 16 + quad * 4);
        bias[cc] = v;
    }

    // octet gather mapping
    const int pair = tid >> 3;            // 0..63 = (p, row)
    const int sub = tid & 7;              // 8 threads per pair
    const int grow = pair & 15;
    const int p = pair >> 4;              // seq sub-position 0..3
    const int e0 = sub * 8;
    const int b_row = bt * 16 + grow;
    // LDS dst: kt = 2p + (sub>>2), quad' = sub&3  ->  k = 64p + 8*sub + j  ✓
    const int goff = (2 * p + (sub >> 2)) * 512 + ((sub & 3) * 16 + grow) * 8;

    auto do_gather = [&](int t) {
        const int seq = t * 4 + p;
        const int v1 = len_x[b_row * SEQN + seq];
        const int v2 = ipd_x[b_row * SEQN + seq];
        const float* lp = lenT + v1 * 64 + e0;
        const float* ip = ipdT + v2 * 64 + e0;
        f32x4 a0 = *(const f32x4*)lp + *(const f32x4*)ip;
        f32x4 a1 = *(const f32x4*)(lp + 4) + *(const f32x4*)(ip + 4);
        bf16x8 o;
        #pragma unroll
        for (int j = 0; j < 4; ++j) { o[j] = (bf16_t)a0[j]; o[4 + j] = (bf16_t)a1[j]; }
        *(bf16x8*)&a_lds[t & 1][goff] = o;
    };

    do_gather(0);
    bf16_t* gib = gi + (size_t)bt * 48 * 32 * 256 + lane * 4;
    const bf16_t* wb = &wlds[w * 8 * 512 + lane * 8];

    for (int t = 0; t < TSTEPS; ++t) {
        barrier_lds();
        if (t + 1 < TSTEPS) do_gather(t + 1);

        f32x4 acc[6];
        #pragma unroll
        for (int cc = 0; cc < 6; ++cc) acc[cc] = bias[cc];   // init from bias

        const bf16_t* ab = &a_lds[t & 1][lane * 8];
        #pragma unroll
        for (int kt = 0; kt < 8; ++kt) {
            bf16x8 xf = *(const bf16x8*)(ab + kt * 512);
            bf16x8 w5 = *(const bf16x8*)(wb + kt * 512);
            acc[0] = MFMA16(wr[0][kt], xf, acc[0]);
            acc[1] = MFMA16(wr[1][kt], xf, acc[1]);
            acc[2] = MFMA16(wr[2][kt], xf, acc[2]);
            acc[3] = MFMA16(wr[3][kt], xf, acc[3]);
            acc[4] = MFMA16(wr[4][kt], xf, acc[4]);
            acc[5] = MFMA16(w5, xf, acc[5]);
        }

        #pragma unroll
        for (int cc = 0; cc < 6; ++cc) {
            u16x4 o;
            #pragma unroll
            for (int r = 0; r < 4; ++r) o[r] = f2b(acc[cc][r]);
            *(u16x4*)(gib + ((size_t)cts[cc] * 32 + t) * 256) = o;   // in flight
        }
    }
}

// ---------------------------------------------------------------------------
// K3: recurrent GRU. 256 blocks x 1024 threads (16 waves, 4/SIMD).
// Wave w owns gate tiles {w, 16+w} in regs + {32+w} (n-gate) in LDS; each
// lane owns 4 CONSECUTIVE hidden cols (gate-major C layout) -> b64 h-write.
// gi prefetched one step ahead; acc INITIALIZED from gi / b_hn (no adds).
// h double-buffered; one lgkm-only barrier per step.
// ---------------------------------------------------------------------------
__global__ void __launch_bounds__(1024, 4)
gru_kernel(const bf16_t* __restrict__ gi,
           const bf16_t* __restrict__ wfrag_hh,
           const float* __restrict__ b_hh,
           const float* __restrict__ out_w,
           const float* __restrict__ out_b,
           float* __restrict__ out) {
    __shared__ char smem[147456];
    bf16_t* wlds = (bf16_t*)smem;                 // 128 KB: per-wave n-tile
    bf16_t* h_lds = (bf16_t*)(smem + 131072);     // 2 x 8 KB double buffer
    float* h_fin = (float*)smem;                  // aliases wlds (post-loop)

    const int tid = threadIdx.x;
    const int lane = tid & 63;
    const int w = tid >> 6;
    const int bt = blockIdx.x;
    const int quad = lane >> 4;
    const int b = lane & 15;

    // tiles: r = w, z = 16+w (regs), n = 32+w (LDS)
    bf16x8 wr[2][8];
    #pragma unroll
    for (int cc = 0; cc < 2; ++cc) {
        const int ct = cc * 16 + w;
        #pragma unroll
        for (int kt = 0; kt < 8; ++kt)
            wr[cc][kt] = *(const bf16x8*)(wfrag_hh + ((ct * 8 + kt) * 64 + lane) * 8);
    }
    #pragma unroll
    for (int kt = 0; kt < 8; ++kt)
        *(bf16x8*)&wlds[(w * 8 + kt) * 512 + lane * 8] =
            *(const bf16x8*)(wfrag_hh + (((32 + w) * 8 + kt) * 64 + lane) * 8);

    // n-gate hidden bias (acc init): rows (32+w)*16 + quad*4 + {0..3}
    const f32x4 bhn = *(const f32x4*)(b_hh + (32 + w) * 16 + quad * 4);

    // zero the t=0 read buffer
    for (int i = tid; i < 4096; i += 1024) h_lds[4096 + i] = (bf16_t)0.f;

    // h-write: lane owns hidden j0 = 16w + 4*quad .. +3 for batch col b
    const int j0 = 16 * w + 4 * quad;
    const int woff = (j0 >> 5) * 512 + ((((j0 >> 3) & 3)) * 16 + b) * 8 + (j0 & 7);

    const bf16_t* gib = gi + (size_t)bt * 48 * 32 * 256 + lane * 4;
    const bf16_t* wb = &wlds[w * 8 * 512 + lane * 8];

    // prefetch g for t=0
    u16x4 gc0 = *(const u16x4*)(gib + ((size_t)(w) * 32) * 256);
    u16x4 gc1 = *(const u16x4*)(gib + ((size_t)(16 + w) * 32) * 256);
    u16x4 gc2 = *(const u16x4*)(gib + ((size_t)(32 + w) * 32) * 256);

    f32x4 hprev = {};   // 4 hidden cols j0..j0+3, batch b

    for (int t = 0; t < TSTEPS; ++t) {
        barrier_lds();                        // prev step's h writes visible

        // acc init: r,z from gi (bias+input pre-folded), n from b_hn
        f32x4 acc0 = b2f4(gc0);
        f32x4 acc1 = b2f4(gc1);
        f32x4 acc2 = bhn;
        u16x4 g2cur = gc2;

        // prefetch next step's gi (consumed at next init; full step of cover)
        if (t + 1 < TSTEPS) {
            gc0 = *(const u16x4*)(gib + ((size_t)(w) * 32 + t + 1) * 256);
            gc1 = *(const u16x4*)(gib + ((size_t)(16 + w) * 32 + t + 1) * 256);
            gc2 = *(const u16x4*)(gib + ((size_t)(32 + w) * 32 + t + 1) * 256);
        }

        const bf16_t* hb = &h_lds[((t + 1) & 1) * 4096 + lane * 8];
        #pragma unroll
        for (int kt = 0; kt < 8; ++kt) {
            bf16x8 hf = *(const bf16x8*)(hb + kt * 512);
            bf16x8 w5 = *(const bf16x8*)(wb + kt * 512);
            acc0 = MFMA16(wr[0][kt], hf, acc0);
            acc1 = MFMA16(wr[1][kt], hf, acc1);
            acc2 = MFMA16(w5, hf, acc2);
        }

        // gate math, f32x4-vectorized (packed fp32 friendly)
        f32x4 rg, zg;
        #pragma unroll
        for (int r = 0; r < 4; ++r) { rg[r] = sigf(acc0[r]); zg[r] = sigf(acc1[r]); }
        f32x4 u = b2f4(g2cur) + rg * acc2;
        f32x4 ng;
        #pragma unroll
        for (int r = 0; r < 4; ++r) ng[r] = tanh_fast(u[r]);
        f32x4 hn = ng + zg * (hprev - ng);
        hprev = hn;

        u16x4 o;
        #pragma unroll
        for (int r = 0; r < 4; ++r) o[r] = f2b(hn[r]);
        *(u16x4*)(&h_lds[(t & 1) * 4096 + woff]) = o;    // one ds_write_b64
    }

    __syncthreads();       // all reads of wlds done -> safe to alias h_fin

    *(f32x4*)(h_fin + b * 260 + j0) = hprev;
    __syncthreads();

    for (int i = tid; i < 16 * NLABELS; i += 1024) {
        const int row = i / NLABELS;
        const int cl = i - row * NLABELS;
        const f32x4* wrow = (const f32x4*)(out_w + cl * 256);
        const f32x4* hr = (const f32x4*)(h_fin + row * 260);
        f32x4 acc = {0.f, 0.f, 0.f, 0.f};
        #pragma unroll 4
        for (int k = 0; k < 64; ++k) acc += hr[k] * wrow[k];
        out[(bt * 16 + row) * NLABELS + cl] =
            out_b[cl] + acc[0] + acc[1] + acc[2] + acc[3];
    }
}

// ---------------------------------------------------------------------------
extern "C" void kernel_launch(void* const* d_in, const int* in_sizes, int n_in,
                              void* d_out, int out_size, void* d_ws, size_t ws_size,
                              hipStream_t stream) {
    (void)in_sizes; (void)n_in; (void)out_size; (void)ws_size;
    const int*   len_x   = (const int*)d_in[0];
    const int*   ipd_x   = (const int*)d_in[1];
    const float* len_emb = (const float*)d_in[2];
    const float* ipd_emb = (const float*)d_in[3];
    const float* fc_w    = (const float*)d_in[4];
    const float* fc_b    = (const float*)d_in[5];
    const float* w_ih    = (const float*)d_in[6];
    const float* w_hh    = (const float*)d_in[7];
    const float* b_ih    = (const float*)d_in[8];
    const float* b_hh    = (const float*)d_in[9];
    const float* out_w   = (const float*)d_in[10];
    const float* out_b   = (const float*)d_in[11];

    char* ws = (char*)d_ws;
    float*  lenT = (float*)(ws + OFF_LENT);
    float*  ipdT = (float*)(ws + OFF_IPDT);
    bf16_t* wfi  = (bf16_t*)(ws + OFF_WIH);
    bf16_t* wfh  = (bf16_t*)(ws + OFF_WHH);
    bf16_t* gi   = (bf16_t*)(ws + OFF_GI);

    prep_kernel<<<631, 256, 0, stream>>>(len_emb, ipd_emb, fc_w, fc_b,
                                         w_ih, w_hh, lenT, ipdT, wfi, wfh);
    gemm_gi<<<256, 512, 0, stream>>>(len_x, ipd_x, lenT, ipdT, wfi,
                                     b_ih, b_hh, gi);
    gru_kernel<<<256, 1024, 0, stream>>>(gi, wfh, b_hh, out_w, out_b,
                                         (float*)d_out);
}